// Round 1
// baseline (1468.768 us; speedup 1.0000x reference)
//
#include <hip/hip_runtime.h>

// Problem constants: B=4, T=2048, C=2048, H=16, D=128
#define T_SEQ 2048
#define DHEAD 128
#define NHEAD 16
#define CDIM  2048
#define BATCH 4

typedef __bf16 v8bf __attribute__((ext_vector_type(8)));
typedef __bf16 v4bf __attribute__((ext_vector_type(4)));
typedef float  v4f  __attribute__((ext_vector_type(4)));

#define MFMA16(a,b,c) __builtin_amdgcn_mfma_f32_16x16x32_bf16(a,b,c,0,0,0)
#define GLDS16(g,l) __builtin_amdgcn_global_load_lds( \
    (__attribute__((address_space(1))) void*)(g), \
    (__attribute__((address_space(3))) void*)(l), 16, 0, 0)

// ---------------- f32 -> bf16 convert (vectorized, grid-stride) --------------
__global__ __launch_bounds__(256) void cvt_f32_bf16(const float* __restrict__ in,
                                                    __bf16* __restrict__ out, int n) {
  int i = blockIdx.x * 256 + threadIdx.x;
  int stride = gridDim.x * 256;
  for (int j = i; 4 * j < n; j += stride) {
    float4 v = *(const float4*)(in + (size_t)j * 4);
    v4bf o = {(__bf16)v.x, (__bf16)v.y, (__bf16)v.z, (__bf16)v.w};
    *(v4bf*)(out + (size_t)j * 4) = o;
  }
}

// ---------------- m97-structure GEMM core: C = A(MxK) * B(NxK)^T -------------
// 128x128 tile, BK=64, 4 waves in 2x2, each wave 64x64 (4x4 of 16x16 frags).
__device__ __forceinline__ void gemm_tile_compute(
    const __bf16* __restrict__ A, const __bf16* __restrict__ B,
    int K, int row0, int col0, v4f (&acc)[4][4]) {
  __shared__ __bf16 lA[128 * 64];
  __shared__ __bf16 lB[128 * 64];
  int t = threadIdx.x;
  int w = t >> 6, l = t & 63;
  int lr = l & 15, lg = l >> 4;
  int wr = (w >> 1) << 6, wc = (w & 1) << 6;
#pragma unroll
  for (int m = 0; m < 4; ++m)
#pragma unroll
    for (int n = 0; n < 4; ++n) acc[m][n] = (v4f){0.f, 0.f, 0.f, 0.f};

  for (int k0 = 0; k0 < K; k0 += 64) {
    // stage A,B tiles: 4 iters x 256 thr x 16B = 16KB each, linear row-major [128][64]
#pragma unroll
    for (int i = 0; i < 4; ++i) {
      int idx = i * 256 + t;
      int r = idx >> 3;
      int ce = (idx & 7) << 3;  // element col (8 bf16 = 16B)
      GLDS16(A + (size_t)(row0 + r) * K + k0 + ce, lA + (size_t)(i * 256 + (w << 6)) * 8);
      GLDS16(B + (size_t)(col0 + r) * K + k0 + ce, lB + (size_t)(i * 256 + (w << 6)) * 8);
    }
    __syncthreads();  // drains vmcnt for global_load_lds
#pragma unroll
    for (int kk = 0; kk < 2; ++kk) {
      v8bf af[4], bfr[4];
#pragma unroll
      for (int m = 0; m < 4; ++m)
        af[m] = *(const v8bf*)&lA[(wr + m * 16 + lr) * 64 + kk * 32 + lg * 8];
#pragma unroll
      for (int n = 0; n < 4; ++n)
        bfr[n] = *(const v8bf*)&lB[(wc + n * 16 + lr) * 64 + kk * 32 + lg * 8];
#pragma unroll
      for (int m = 0; m < 4; ++m)
#pragma unroll
        for (int n = 0; n < 4; ++n)
          acc[m][n] = MFMA16(af[m], bfr[n], acc[m][n]);
    }
    __syncthreads();
  }
}

// GEMM1: qkv = x * w_attn^T + b_attn, epilogue scatters to Q,K (BH,T,D) and Vt (BH,D,T), bf16
__global__ __launch_bounds__(256) void gemm_qkv(
    const __bf16* __restrict__ A, const __bf16* __restrict__ B,
    const float* __restrict__ bias,
    __bf16* __restrict__ Qb, __bf16* __restrict__ Kb, __bf16* __restrict__ Vt) {
  v4f acc[4][4];
  int row0 = blockIdx.x * 128, col0 = blockIdx.y * 128;
  gemm_tile_compute(A, B, CDIM, row0, col0, acc);
  int t = threadIdx.x, w = t >> 6, l = t & 63;
  int lr = l & 15, lg = l >> 4;
  int wr = (w >> 1) << 6, wc = (w & 1) << 6;
  int tensor = col0 >> 11;        // 0=q 1=k 2=v (tile never spans a boundary: 128|2048)
  int h = (col0 & 2047) >> 7;     // head (tile is exactly one head's 128 cols)
#pragma unroll
  for (int n = 0; n < 4; ++n) {
    int d = wc + n * 16 + lr;     // 0..127 within head
    float bv = bias[col0 + d];
#pragma unroll
    for (int m = 0; m < 4; ++m) {
#pragma unroll
      for (int r = 0; r < 4; ++r) {
        int mg = row0 + wr + m * 16 + lg * 4 + r;   // global row in [0, B*T)
        int b = mg >> 11, tt = mg & 2047;
        float v = acc[m][n][r] + bv;
        size_t bh = (size_t)(b * NHEAD + h);
        if (tensor == 0)      Qb[(bh * T_SEQ + tt) * DHEAD + d] = (__bf16)v;
        else if (tensor == 1) Kb[(bh * T_SEQ + tt) * DHEAD + d] = (__bf16)v;
        else                  Vt[(bh * DHEAD + d) * T_SEQ + tt] = (__bf16)v;
      }
    }
  }
}

// GEMM2: out = Y * w_proj^T + b_proj, fp32 row-major epilogue
__global__ __launch_bounds__(256) void gemm_out(
    const __bf16* __restrict__ A, const __bf16* __restrict__ B,
    const float* __restrict__ bias, float* __restrict__ C) {
  v4f acc[4][4];
  int row0 = blockIdx.x * 128, col0 = blockIdx.y * 128;
  gemm_tile_compute(A, B, CDIM, row0, col0, acc);
  int t = threadIdx.x, w = t >> 6, l = t & 63;
  int lr = l & 15, lg = l >> 4;
  int wr = (w >> 1) << 6, wc = (w & 1) << 6;
#pragma unroll
  for (int n = 0; n < 4; ++n) {
    int col = col0 + wc + n * 16 + lr;
    float bv = bias[col];
#pragma unroll
    for (int m = 0; m < 4; ++m) {
#pragma unroll
      for (int r = 0; r < 4; ++r) {
        int mg = row0 + wr + m * 16 + lg * 4 + r;
        C[(size_t)mg * CDIM + col] = acc[m][n][r] + bv;
      }
    }
  }
}

// ---------------- RoPE in-place on Q,K (BH,T,D) ------------------------------
// out[j]    = x[j]*(c+s)    - x[2j+1]*(c-s)     (j < 64)
// out[j+64] = x[j+64]*(c+s) + x[2j]*(c-s)
__global__ __launch_bounds__(256) void rope_kernel(__bf16* __restrict__ Qb,
                                                   __bf16* __restrict__ Kb) {
  int idx = blockIdx.x * 256 + threadIdx.x;          // 0 .. 262143
  __bf16* base = (idx & 131072) ? Kb : Qb;
  int r = idx & 131071;                              // row within (BH*T)
  int tt = r & (T_SEQ - 1);
  __bf16* p = base + (size_t)r * DHEAD;
  v8bf xv[16];
#pragma unroll
  for (int j = 0; j < 16; ++j) xv[j] = *(const v8bf*)&p[j * 8];
  v8bf ov[16];
#pragma unroll
  for (int j = 0; j < 64; ++j) {
    float invf = exp2f((float)j * (-13.287712379549449f / 64.f));  // 10000^(-j/64)
    float ang = (float)tt * invf;
    float c = cosf(ang), s = sinf(ang);
    float cps = c + s, cms = c - s;
    float xj   = (float)xv[j >> 3][j & 7];
    float xj64 = (float)xv[(j + 64) >> 3][j & 7];
    float x2j  = (float)xv[(2 * j) >> 3][(2 * j) & 7];
    float x2j1 = (float)xv[(2 * j + 1) >> 3][(2 * j + 1) & 7];
    ov[j >> 3][j & 7]        = (__bf16)(xj * cps - x2j1 * cms);
    ov[(j + 64) >> 3][j & 7] = (__bf16)(xj64 * cps + x2j * cms);
  }
#pragma unroll
  for (int j = 0; j < 16; ++j) *(v8bf*)&p[j * 8] = ov[j];
}

// ---------------- flash attention ------------------------------------------
// grid (T/64, B*H), 256 thr. Wave w: 16 q-rows at q0 = bx*64 + w*16.
// Swapped QK^T: mfma(K,Q) -> lane holds S[kv = kv0+lg*4+reg][q = q0+lr].
// Softmax state per-lane (one q-row). P via per-wave LDS -> K=32 PV A-frag.
__global__ __launch_bounds__(256) void attn_fwd(
    const __bf16* __restrict__ Qb, const __bf16* __restrict__ Kb,
    const __bf16* __restrict__ Vt, __bf16* __restrict__ Y) {
  __shared__ __bf16 plds[4][16][32];
  int t = threadIdx.x, w = t >> 6, l = t & 63;
  int lr = l & 15, lg = l >> 4;
  int bh = blockIdx.y;
  int b = bh >> 4, h = bh & 15;
  int q0 = blockIdx.x * 64 + w * 16;
  const __bf16* Qh = Qb + (size_t)bh * T_SEQ * DHEAD;
  const __bf16* Kh = Kb + (size_t)bh * T_SEQ * DHEAD;
  const __bf16* Vh = Vt + (size_t)bh * DHEAD * T_SEQ;

  v8bf qf[4];
#pragma unroll
  for (int c = 0; c < 4; ++c)
    qf[c] = *(const v8bf*)&Qh[(size_t)(q0 + lr) * DHEAD + c * 32 + lg * 8];

  v4f o[8];
#pragma unroll
  for (int c = 0; c < 8; ++c) o[c] = (v4f){0.f, 0.f, 0.f, 0.f};
  float mrow = -1e30f, lrow = 0.f;
  const float scale = 0.08838834764831845f;  // 1/sqrt(128)
  int qg = q0 + lr;

  for (int kv0 = 0; kv0 < q0 + 16; kv0 += 32) {
    v4f s0 = (v4f){0.f, 0.f, 0.f, 0.f}, s1 = (v4f){0.f, 0.f, 0.f, 0.f};
#pragma unroll
    for (int c = 0; c < 4; ++c) {
      v8bf kf0 = *(const v8bf*)&Kh[(size_t)(kv0 + lr) * DHEAD + c * 32 + lg * 8];
      v8bf kf1 = *(const v8bf*)&Kh[(size_t)(kv0 + 16 + lr) * DHEAD + c * 32 + lg * 8];
      s0 = MFMA16(kf0, qf[c], s0);
      s1 = MFMA16(kf1, qf[c], s1);
    }
    float p[8];
    float mt = -1e30f;
#pragma unroll
    for (int r = 0; r < 4; ++r) {
      float v0 = s0[r] * scale;
      if (kv0 + lg * 4 + r > qg) v0 = -1e30f;
      float v1 = s1[r] * scale;
      if (kv0 + 16 + lg * 4 + r > qg) v1 = -1e30f;
      p[r] = v0; p[4 + r] = v1;
      mt = fmaxf(mt, fmaxf(v0, v1));
    }
    mt = fmaxf(mt, __shfl_xor(mt, 16));
    mt = fmaxf(mt, __shfl_xor(mt, 32));
    float mnew = fmaxf(mrow, mt);
    float corr = __expf(mrow - mnew);
    float psum = 0.f;
#pragma unroll
    for (int r = 0; r < 8; ++r) { p[r] = __expf(p[r] - mnew); psum += p[r]; }
    psum += __shfl_xor(psum, 16);
    psum += __shfl_xor(psum, 32);
    lrow = lrow * corr + psum;
    mrow = mnew;
    // P -> LDS (per-wave), re-read in K=32 A-frag layout
    v4bf pv0 = {(__bf16)p[0], (__bf16)p[1], (__bf16)p[2], (__bf16)p[3]};
    v4bf pv1 = {(__bf16)p[4], (__bf16)p[5], (__bf16)p[6], (__bf16)p[7]};
    *(v4bf*)&plds[w][lr][lg * 4]      = pv0;
    *(v4bf*)&plds[w][lr][16 + lg * 4] = pv1;
    asm volatile("s_waitcnt lgkmcnt(0)" ::: "memory");
    v8bf pa = *(const v8bf*)&plds[w][lr][lg * 8];
    // rescale accumulators (acc q-row = lg*4+r; corr lives at lane lg*4+r)
    float cf[4];
#pragma unroll
    for (int r = 0; r < 4; ++r) cf[r] = __shfl(corr, lg * 4 + r);
#pragma unroll
    for (int c = 0; c < 8; ++c)
#pragma unroll
      for (int r = 0; r < 4; ++r) o[c][r] *= cf[r];
    // PV: out[q][d] += P[q][kv] * Vt[d][kv]^T
#pragma unroll
    for (int c = 0; c < 8; ++c) {
      v8bf vf = *(const v8bf*)&Vh[(size_t)(c * 16 + lr) * T_SEQ + kv0 + lg * 8];
      o[c] = MFMA16(pa, vf, o[c]);
    }
  }
  float lf[4];
#pragma unroll
  for (int r = 0; r < 4; ++r) lf[r] = __shfl(lrow, lg * 4 + r);
  size_t ybase = ((size_t)b * T_SEQ) * CDIM + (size_t)h * DHEAD;
#pragma unroll
  for (int c = 0; c < 8; ++c) {
#pragma unroll
    for (int r = 0; r < 4; ++r) {
      int qq = q0 + lg * 4 + r;
      Y[ybase + (size_t)qq * CDIM + c * 16 + lr] = (__bf16)(o[c][r] / lf[r]);
    }
  }
}

// ---------------- launch -----------------------------------------------------
extern "C" void kernel_launch(void* const* d_in, const int* in_sizes, int n_in,
                              void* d_out, int out_size, void* d_ws, size_t ws_size,
                              hipStream_t stream) {
  const float* x      = (const float*)d_in[0];
  const float* w_attn = (const float*)d_in[1];
  const float* b_attn = (const float*)d_in[2];
  const float* w_proj = (const float*)d_in[3];
  const float* b_proj = (const float*)d_in[4];
  float* out = (float*)d_out;

  char* ws = (char*)d_ws;
  __bf16* xbf  = (__bf16*)(ws);                 // 33,554,432 B (B*T*C bf16); reused as Y
  __bf16* wabf = (__bf16*)(ws + 33554432);      // 25,165,824 B
  __bf16* wpbf = (__bf16*)(ws + 58720256);      //  8,388,608 B
  __bf16* Qb   = (__bf16*)(ws + 67108864);      // 33,554,432 B (BH,T,D)
  __bf16* Kb   = (__bf16*)(ws + 100663296);     // 33,554,432 B (BH,T,D)
  __bf16* Vt   = (__bf16*)(ws + 134217728);     // 33,554,432 B (BH,D,T)  [total 160 MB]
  __bf16* Y    = xbf;                           // alias: xbf dead after gemm_qkv

  cvt_f32_bf16<<<1024, 256, 0, stream>>>(x, xbf, 16777216);
  cvt_f32_bf16<<<1024, 256, 0, stream>>>(w_attn, wabf, 12582912);
  cvt_f32_bf16<<<512, 256, 0, stream>>>(w_proj, wpbf, 4194304);

  gemm_qkv<<<dim3(64, 48), 256, 0, stream>>>(xbf, wabf, b_attn, Qb, Kb, Vt);

  rope_kernel<<<1024, 256, 0, stream>>>(Qb, Kb);

  attn_fwd<<<dim3(32, 64), 256, 0, stream>>>(Qb, Kb, Vt, Y);

  gemm_out<<<dim3(64, 16), 256, 0, stream>>>(Y, wpbf, b_proj, out);
}

// Round 2
// 807.998 us; speedup vs baseline: 1.8178x; 1.8178x over previous
//
#include <hip/hip_runtime.h>

// Problem constants: B=4, T=2048, C=2048, H=16, D=128
#define T_SEQ 2048
#define DHEAD 128
#define NHEAD 16
#define CDIM  2048
#define BATCH 4

typedef __bf16 v8bf __attribute__((ext_vector_type(8)));
typedef __bf16 v4bf __attribute__((ext_vector_type(4)));
typedef float  v4f  __attribute__((ext_vector_type(4)));

#define MFMA16(a,b,c) __builtin_amdgcn_mfma_f32_16x16x32_bf16(a,b,c,0,0,0)
#define GLDS16(g,l) __builtin_amdgcn_global_load_lds( \
    (__attribute__((address_space(1))) void*)(g), \
    (__attribute__((address_space(3))) void*)(l), 16, 0, 0)

// ---------------- f32 -> bf16 convert (vectorized, grid-stride) --------------
__global__ __launch_bounds__(256) void cvt_f32_bf16(const float* __restrict__ in,
                                                    __bf16* __restrict__ out, int n) {
  int i = blockIdx.x * 256 + threadIdx.x;
  int stride = gridDim.x * 256;
  for (int j = i; 4 * j < n; j += stride) {
    float4 v = *(const float4*)(in + (size_t)j * 4);
    v4bf o = {(__bf16)v.x, (__bf16)v.y, (__bf16)v.z, (__bf16)v.w};
    *(v4bf*)(out + (size_t)j * 4) = o;
  }
}

// ---------------- m97-structure GEMM core: C = A(MxK) * B(NxK)^T -------------
// 128x128 tile, BK=64, 4 waves in 2x2, each wave 64x64 (4x4 of 16x16 frags).
__device__ __forceinline__ void gemm_tile_compute(
    const __bf16* __restrict__ A, const __bf16* __restrict__ B,
    int K, int row0, int col0, v4f (&acc)[4][4]) {
  __shared__ __bf16 lA[128 * 64];
  __shared__ __bf16 lB[128 * 64];
  int t = threadIdx.x;
  int w = t >> 6, l = t & 63;
  int lr = l & 15, lg = l >> 4;
  int wr = (w >> 1) << 6, wc = (w & 1) << 6;
#pragma unroll
  for (int m = 0; m < 4; ++m)
#pragma unroll
    for (int n = 0; n < 4; ++n) acc[m][n] = (v4f){0.f, 0.f, 0.f, 0.f};

  for (int k0 = 0; k0 < K; k0 += 64) {
#pragma unroll
    for (int i = 0; i < 4; ++i) {
      int idx = i * 256 + t;
      int r = idx >> 3;
      int ce = (idx & 7) << 3;  // element col (8 bf16 = 16B)
      GLDS16(A + (size_t)(row0 + r) * K + k0 + ce, lA + (size_t)(i * 256 + (w << 6)) * 8);
      GLDS16(B + (size_t)(col0 + r) * K + k0 + ce, lB + (size_t)(i * 256 + (w << 6)) * 8);
    }
    __syncthreads();  // drains vmcnt for global_load_lds
#pragma unroll
    for (int kk = 0; kk < 2; ++kk) {
      v8bf af[4], bfr[4];
#pragma unroll
      for (int m = 0; m < 4; ++m)
        af[m] = *(const v8bf*)&lA[(wr + m * 16 + lr) * 64 + kk * 32 + lg * 8];
#pragma unroll
      for (int n = 0; n < 4; ++n)
        bfr[n] = *(const v8bf*)&lB[(wc + n * 16 + lr) * 64 + kk * 32 + lg * 8];
#pragma unroll
      for (int m = 0; m < 4; ++m)
#pragma unroll
        for (int n = 0; n < 4; ++n)
          acc[m][n] = MFMA16(af[m], bfr[n], acc[m][n]);
    }
    __syncthreads();
  }
}

// GEMM1: qkv = x * w_attn^T + b_attn, epilogue scatters to Q,K (BH,T,D) and Vt (BH,D,T), bf16
__global__ __launch_bounds__(256) void gemm_qkv(
    const __bf16* __restrict__ A, const __bf16* __restrict__ B,
    const float* __restrict__ bias,
    __bf16* __restrict__ Qb, __bf16* __restrict__ Kb, __bf16* __restrict__ Vt) {
  v4f acc[4][4];
  int row0 = blockIdx.x * 128, col0 = blockIdx.y * 128;
  gemm_tile_compute(A, B, CDIM, row0, col0, acc);
  int t = threadIdx.x, w = t >> 6, l = t & 63;
  int lr = l & 15, lg = l >> 4;
  int wr = (w >> 1) << 6, wc = (w & 1) << 6;
  int tensor = col0 >> 11;        // 0=q 1=k 2=v
  int h = (col0 & 2047) >> 7;     // head
#pragma unroll
  for (int n = 0; n < 4; ++n) {
    int d = wc + n * 16 + lr;     // 0..127 within head
    float bv = bias[col0 + d];
#pragma unroll
    for (int m = 0; m < 4; ++m) {
#pragma unroll
      for (int r = 0; r < 4; ++r) {
        int mg = row0 + wr + m * 16 + lg * 4 + r;   // global row in [0, B*T)
        int b = mg >> 11, tt = mg & 2047;
        float v = acc[m][n][r] + bv;
        size_t bh = (size_t)(b * NHEAD + h);
        if (tensor == 0)      Qb[(bh * T_SEQ + tt) * DHEAD + d] = (__bf16)v;
        else if (tensor == 1) Kb[(bh * T_SEQ + tt) * DHEAD + d] = (__bf16)v;
        else                  Vt[(bh * DHEAD + d) * T_SEQ + tt] = (__bf16)v;
      }
    }
  }
}

// GEMM2: out = Y * w_proj^T + b_proj, fp32 row-major epilogue
__global__ __launch_bounds__(256) void gemm_out(
    const __bf16* __restrict__ A, const __bf16* __restrict__ B,
    const float* __restrict__ bias, float* __restrict__ C) {
  v4f acc[4][4];
  int row0 = blockIdx.x * 128, col0 = blockIdx.y * 128;
  gemm_tile_compute(A, B, CDIM, row0, col0, acc);
  int t = threadIdx.x, w = t >> 6, l = t & 63;
  int lr = l & 15, lg = l >> 4;
  int wr = (w >> 1) << 6, wc = (w & 1) << 6;
#pragma unroll
  for (int n = 0; n < 4; ++n) {
    int col = col0 + wc + n * 16 + lr;
    float bv = bias[col];
#pragma unroll
    for (int m = 0; m < 4; ++m) {
#pragma unroll
      for (int r = 0; r < 4; ++r) {
        int mg = row0 + wr + m * 16 + lg * 4 + r;
        C[(size_t)mg * CDIM + col] = acc[m][n][r] + bv;
      }
    }
  }
}

// ---------------- RoPE in-place on Q,K (BH,T,D) ------------------------------
__global__ __launch_bounds__(256) void rope_kernel(__bf16* __restrict__ Qb,
                                                   __bf16* __restrict__ Kb) {
  int idx = blockIdx.x * 256 + threadIdx.x;          // 0 .. 262143
  __bf16* base = (idx & 131072) ? Kb : Qb;
  int r = idx & 131071;                              // row within (BH*T)
  int tt = r & (T_SEQ - 1);
  __bf16* p = base + (size_t)r * DHEAD;
  v8bf xv[16];
#pragma unroll
  for (int j = 0; j < 16; ++j) xv[j] = *(const v8bf*)&p[j * 8];
  v8bf ov[16];
#pragma unroll
  for (int j = 0; j < 64; ++j) {
    float invf = exp2f((float)j * (-13.287712379549449f / 64.f));  // 10000^(-j/64)
    float ang = (float)tt * invf;
    float c = cosf(ang), s = sinf(ang);
    float cps = c + s, cms = c - s;
    float xj   = (float)xv[j >> 3][j & 7];
    float xj64 = (float)xv[(j + 64) >> 3][j & 7];
    float x2j  = (float)xv[(2 * j) >> 3][(2 * j) & 7];
    float x2j1 = (float)xv[(2 * j + 1) >> 3][(2 * j + 1) & 7];
    ov[j >> 3][j & 7]        = (__bf16)(xj * cps - x2j1 * cms);
    ov[(j + 64) >> 3][j & 7] = (__bf16)(xj64 * cps + x2j * cms);
  }
#pragma unroll
  for (int j = 0; j < 16; ++j) *(v8bf*)&p[j * 8] = ov[j];
}

// ---------------- flash attention (v2: LDS-staged K/V, 32 q-rows/wave) ------
// grid (T/128, B*H) with bx reversed (heavy tiles first), 256 thr = 4 waves.
// Block covers 128 q-rows; wave w owns rows [qb + w*32, qb + w*32 + 32).
// KV tiles of 64 staged in LDS (K [64][128], V [128][64]) via global_load_lds
// with inverse-swizzled global source; reads use byte ^= ((row&7)<<4).
// Swapped QK^T: mfma(K,Q) -> lane owns q-row j*16+lr per fragment j in {0,1}.
__global__ __launch_bounds__(256) void attn_fwd(
    const __bf16* __restrict__ Qb, const __bf16* __restrict__ Kb,
    const __bf16* __restrict__ Vt, __bf16* __restrict__ Y) {
  __shared__ __bf16 lK[64 * 128];       // 16 KB, [kv][d] swizzled
  __shared__ __bf16 lV[128 * 64];       // 16 KB, [d][kv] swizzled
  __shared__ __bf16 plds[4][32][72];    // 18 KB, per-wave P, padded rows
  int t = threadIdx.x, w = t >> 6, l = t & 63;
  int lr = l & 15, lg = l >> 4;
  int bh = blockIdx.y;
  int b = bh >> 4, h = bh & 15;
  int qb = ((int)gridDim.x - 1 - (int)blockIdx.x) * 128;  // heavy first
  int q0 = qb + w * 32;
  const __bf16* Qh = Qb + (size_t)bh * T_SEQ * DHEAD;
  const __bf16* Kh = Kb + (size_t)bh * T_SEQ * DHEAD;
  const __bf16* Vh = Vt + (size_t)bh * DHEAD * T_SEQ;

  // Q fragments: 2 x 16 q-rows
  v8bf qf[2][4];
#pragma unroll
  for (int j = 0; j < 2; ++j)
#pragma unroll
    for (int c = 0; c < 4; ++c)
      qf[j][c] = *(const v8bf*)&Qh[(size_t)(q0 + j * 16 + lr) * DHEAD + c * 32 + lg * 8];

  v4f o[2][8];
#pragma unroll
  for (int j = 0; j < 2; ++j)
#pragma unroll
    for (int c = 0; c < 8; ++c) o[j][c] = (v4f){0.f, 0.f, 0.f, 0.f};
  float mrow[2] = {-1e30f, -1e30f}, lrow[2] = {0.f, 0.f};
  const float scale = 0.08838834764831845f;  // 1/sqrt(128)

  // staging source offsets (inverse-swizzle, constant across rounds since
  // round stride is a multiple of 8 rows)
  int kRow = t >> 4;                                  // + i*16
  int kSrc = (((t & 15) * 16) ^ ((kRow & 7) << 4)) >> 1;   // elements
  int vRow = t >> 3;                                  // + i*32
  int vSrc = (((t & 7) * 16) ^ ((vRow & 7) << 4)) >> 1;    // elements

  int kvEnd = qb + 64;  // last kv tile base
  for (int kv0 = 0; kv0 <= kvEnd; kv0 += 64) {
    __syncthreads();  // prev tile fully consumed before overwrite
#pragma unroll
    for (int i = 0; i < 4; ++i) {
      GLDS16(Kh + (size_t)(kv0 + i * 16 + kRow) * DHEAD + kSrc,
             lK + i * 2048 + w * 512);
      GLDS16(Vh + (size_t)(i * 32 + vRow) * T_SEQ + kv0 + vSrc,
             lV + i * 2048 + w * 512);
    }
    __syncthreads();  // vmcnt drained by compiler before barrier

    // ---- QK^T: S[64 kv][32 q] via swapped operands ----
    v4f s[2][4];
#pragma unroll
    for (int j = 0; j < 2; ++j)
#pragma unroll
      for (int f = 0; f < 4; ++f) s[j][f] = (v4f){0.f, 0.f, 0.f, 0.f};
#pragma unroll
    for (int f = 0; f < 4; ++f) {
      int row = f * 16 + lr;
      int sw = (row & 7) << 4;
#pragma unroll
      for (int c = 0; c < 4; ++c) {
        v8bf kf = *(const v8bf*)((const char*)lK + row * 256 + ((c * 64 + lg * 16) ^ sw));
        s[0][f] = MFMA16(kf, qf[0][c], s[0][f]);
        s[1][f] = MFMA16(kf, qf[1][c], s[1][f]);
      }
    }

    // ---- online softmax per q-fragment ----
#pragma unroll
    for (int j = 0; j < 2; ++j) {
      int qg = q0 + j * 16 + lr;
      float p[16];
      float mt = -1e30f;
#pragma unroll
      for (int f = 0; f < 4; ++f)
#pragma unroll
        for (int r = 0; r < 4; ++r) {
          float v = s[j][f][r] * scale;
          if (kv0 + f * 16 + lg * 4 + r > qg) v = -1e30f;
          p[f * 4 + r] = v;
          mt = fmaxf(mt, v);
        }
      mt = fmaxf(mt, __shfl_xor(mt, 16));
      mt = fmaxf(mt, __shfl_xor(mt, 32));
      float mnew = fmaxf(mrow[j], mt);
      float corr = __expf(mrow[j] - mnew);
      float psum = 0.f;
#pragma unroll
      for (int r = 0; r < 16; ++r) { p[r] = __expf(p[r] - mnew); psum += p[r]; }
      psum += __shfl_xor(psum, 16);
      psum += __shfl_xor(psum, 32);
      lrow[j] = lrow[j] * corr + psum;
      mrow[j] = mnew;
      // P -> per-wave LDS
#pragma unroll
      for (int f = 0; f < 4; ++f) {
        v4bf pv = {(__bf16)p[f * 4], (__bf16)p[f * 4 + 1],
                   (__bf16)p[f * 4 + 2], (__bf16)p[f * 4 + 3]};
        *(v4bf*)&plds[w][j * 16 + lr][f * 16 + lg * 4] = pv;
      }
      // rescale accumulators (acc q-row = lg*4+r)
      float cf[4];
#pragma unroll
      for (int r = 0; r < 4; ++r) cf[r] = __shfl(corr, lg * 4 + r);
#pragma unroll
      for (int c = 0; c < 8; ++c)
#pragma unroll
        for (int r = 0; r < 4; ++r) o[j][c][r] *= cf[r];
    }

    // ---- PV: O[32 q][128 d] += P[32][64] * V[64][128] ----
    v8bf pa[2][2];
#pragma unroll
    for (int j = 0; j < 2; ++j) {
      pa[j][0] = *(const v8bf*)&plds[w][j * 16 + lr][lg * 8];
      pa[j][1] = *(const v8bf*)&plds[w][j * 16 + lr][32 + lg * 8];
    }
#pragma unroll
    for (int c = 0; c < 8; ++c) {
      int row = c * 16 + lr;
      int sw = (row & 7) << 4;
      v8bf vf0 = *(const v8bf*)((const char*)lV + row * 128 + ((lg * 16) ^ sw));
      v8bf vf1 = *(const v8bf*)((const char*)lV + row * 128 + ((64 + lg * 16) ^ sw));
      o[0][c] = MFMA16(pa[0][0], vf0, o[0][c]);
      o[0][c] = MFMA16(pa[0][1], vf1, o[0][c]);
      o[1][c] = MFMA16(pa[1][0], vf0, o[1][c]);
      o[1][c] = MFMA16(pa[1][1], vf1, o[1][c]);
    }
  }

  // ---- epilogue: divide by l, write Y (B,T,C) ----
  size_t ybase = ((size_t)b * T_SEQ) * CDIM + (size_t)h * DHEAD;
#pragma unroll
  for (int j = 0; j < 2; ++j) {
    float lf[4];
#pragma unroll
    for (int r = 0; r < 4; ++r) lf[r] = __shfl(lrow[j], lg * 4 + r);
#pragma unroll
    for (int c = 0; c < 8; ++c) {
#pragma unroll
      for (int r = 0; r < 4; ++r) {
        int qq = q0 + j * 16 + lg * 4 + r;
        Y[ybase + (size_t)qq * CDIM + c * 16 + lr] = (__bf16)(o[j][c][r] / lf[r]);
      }
    }
  }
}

// ---------------- launch -----------------------------------------------------
extern "C" void kernel_launch(void* const* d_in, const int* in_sizes, int n_in,
                              void* d_out, int out_size, void* d_ws, size_t ws_size,
                              hipStream_t stream) {
  const float* x      = (const float*)d_in[0];
  const float* w_attn = (const float*)d_in[1];
  const float* b_attn = (const float*)d_in[2];
  const float* w_proj = (const float*)d_in[3];
  const float* b_proj = (const float*)d_in[4];
  float* out = (float*)d_out;

  char* ws = (char*)d_ws;
  __bf16* xbf  = (__bf16*)(ws);                 // 33,554,432 B; reused as Y
  __bf16* wabf = (__bf16*)(ws + 33554432);      // 25,165,824 B
  __bf16* wpbf = (__bf16*)(ws + 58720256);      //  8,388,608 B
  __bf16* Qb   = (__bf16*)(ws + 67108864);      // 33,554,432 B (BH,T,D)
  __bf16* Kb   = (__bf16*)(ws + 100663296);     // 33,554,432 B (BH,T,D)
  __bf16* Vt   = (__bf16*)(ws + 134217728);     // 33,554,432 B (BH,D,T)
  __bf16* Y    = xbf;

  cvt_f32_bf16<<<1024, 256, 0, stream>>>(x, xbf, 16777216);
  cvt_f32_bf16<<<1024, 256, 0, stream>>>(w_attn, wabf, 12582912);
  cvt_f32_bf16<<<512, 256, 0, stream>>>(w_proj, wpbf, 4194304);

  gemm_qkv<<<dim3(64, 48), 256, 0, stream>>>(xbf, wabf, b_attn, Qb, Kb, Vt);

  rope_kernel<<<1024, 256, 0, stream>>>(Qb, Kb);

  attn_fwd<<<dim3(16, 64), 256, 0, stream>>>(Qb, Kb, Vt, Y);

  gemm_out<<<dim3(64, 16), 256, 0, stream>>>(Y, wpbf, b_proj, out);
}

// Round 3
// 658.666 us; speedup vs baseline: 2.2299x; 1.2267x over previous
//
#include <hip/hip_runtime.h>

// Problem constants: B=4, T=2048, C=2048, H=16, D=128
#define T_SEQ 2048
#define DHEAD 128
#define NHEAD 16
#define CDIM  2048
#define BATCH 4

typedef __bf16 v8bf __attribute__((ext_vector_type(8)));
typedef __bf16 v4bf __attribute__((ext_vector_type(4)));
typedef float  v4f  __attribute__((ext_vector_type(4)));

#define MFMA16(a,b,c) __builtin_amdgcn_mfma_f32_16x16x32_bf16(a,b,c,0,0,0)
#define GLDS16(g,l) __builtin_amdgcn_global_load_lds( \
    (__attribute__((address_space(1))) void*)(g), \
    (__attribute__((address_space(3))) void*)(l), 16, 0, 0)

// ---------------- f32 -> bf16 convert (vectorized, grid-stride) --------------
__global__ __launch_bounds__(256) void cvt_f32_bf16(const float* __restrict__ in,
                                                    __bf16* __restrict__ out, int n) {
  int i = blockIdx.x * 256 + threadIdx.x;
  int stride = gridDim.x * 256;
  for (int j = i; 4 * j < n; j += stride) {
    float4 v = *(const float4*)(in + (size_t)j * 4);
    v4bf o = {(__bf16)v.x, (__bf16)v.y, (__bf16)v.z, (__bf16)v.w};
    *(v4bf*)(out + (size_t)j * 4) = o;
  }
}

// =============== 256x256 8-phase GEMM core (m201 template, plain HIP) =======
// C = A(8192 x 2048) * B(N x 2048)^T, 256x256 tile, BK=64, 8 waves (2Mx4N).
// Dynamic LDS 128 KiB: 2 bufs x (A 256x64 + B 256x64) bf16.
// Per K-tile: 4 phases {ds_read frags | stage 1 half-tile | bar | lgkm0 |
// setprio(1) 16 MFMA setprio(0) | bar}; vmcnt(6) once per tile (3 half-tiles
// in flight). LDS reads XOR-swizzled byte^=(lr&7)<<4; staging keeps LDS dest
// linear and inverse-swizzles the global source column (guide rule #21).
// A m-frag rows interleaved: row = wm*16 + m*32 -> rows [0,64p) consumed by
// end of phase p, making the 3-slot-lookahead stage schedule race-free.

#define LGKM0() { asm volatile("s_waitcnt lgkmcnt(0)" ::: "memory"); \
                  __builtin_amdgcn_sched_barrier(0); }
#define BARR()  { __builtin_amdgcn_s_barrier(); __builtin_amdgcn_sched_barrier(0); }

#define RDA(mm, kk) (*(const v8bf*)(bA + (wm16 + (mm)*32 + lr) * 128 + ((((kk)*64) + lgc) ^ swl)))
#define RDB(n, kk)  (*(const v8bf*)(bB + (wn64 + (n)*16 + lr) * 128 + ((((kk)*64) + lgc) ^ swl)))
#define MF(mm,n,kk) acc[mm][n] = MFMA16(af[(mm)&1][kk], bfr[n][kk], acc[mm][n]);

#define PH_MFMA(MM0, MM1) \
  BARR(); LGKM0(); \
  __builtin_amdgcn_s_setprio(1); \
  MF(MM0,0,0) MF(MM0,1,0) MF(MM0,2,0) MF(MM0,3,0) \
  MF(MM1,0,0) MF(MM1,1,0) MF(MM1,2,0) MF(MM1,3,0) \
  MF(MM0,0,1) MF(MM0,1,1) MF(MM0,2,1) MF(MM0,3,1) \
  MF(MM1,0,1) MF(MM1,1,1) MF(MM1,2,1) MF(MM1,3,1) \
  __builtin_amdgcn_s_setprio(0); \
  BARR();

// Stage one half-tile (128 rows x 64 cols bf16 = 16KB): 2 x GLDS16 per thread.
// SRC already includes (panel row0 + srow) * 2048 + scol (inverse-swizzled).
#define STAGE_H(SRC, ks, hh, LBASE) { \
  GLDS16((SRC) + (size_t)((hh)*128)      * 2048 + (size_t)(ks)*64, lds + (LBASE) + dst0); \
  GLDS16((SRC) + (size_t)((hh)*128 + 64) * 2048 + (size_t)(ks)*64, lds + (LBASE) + 4096 + dst0); }

// One K-tile: compute from buf CB; stage Ah1(ks1)->buf CB^1, and
// Bh0/Ah0/Bh1(ks2)->buf CB at phases 2/3/4.
#define TILE(CB, ks1, ks2) { \
  const char* bA = (const char*)(lds + (CB)*32768); \
  const char* bB = bA + 32768; \
  v8bf bfr[4][2], af[2][2]; \
  /* phase 1: mm 0,1 + all B-frags */ \
  af[0][0]=RDA(0,0); af[0][1]=RDA(0,1); af[1][0]=RDA(1,0); af[1][1]=RDA(1,1); \
  bfr[0][0]=RDB(0,0); bfr[0][1]=RDB(0,1); bfr[1][0]=RDB(1,0); bfr[1][1]=RDB(1,1); \
  bfr[2][0]=RDB(2,0); bfr[2][1]=RDB(2,1); bfr[3][0]=RDB(3,0); bfr[3][1]=RDB(3,1); \
  STAGE_H(Asrc, ks1, 1, ((CB)^1)*32768 + 8192); \
  PH_MFMA(0, 1) \
  /* phase 2: mm 2,3 */ \
  af[0][0]=RDA(2,0); af[0][1]=RDA(2,1); af[1][0]=RDA(3,0); af[1][1]=RDA(3,1); \
  STAGE_H(Bsrc, ks2, 0, (CB)*32768 + 16384); \
  PH_MFMA(2, 3) \
  /* phase 3: mm 4,5 */ \
  af[0][0]=RDA(4,0); af[0][1]=RDA(4,1); af[1][0]=RDA(5,0); af[1][1]=RDA(5,1); \
  STAGE_H(Asrc, ks2, 0, (CB)*32768); \
  PH_MFMA(4, 5) \
  /* phase 4: mm 6,7 + counted vmcnt */ \
  af[0][0]=RDA(6,0); af[0][1]=RDA(6,1); af[1][0]=RDA(7,0); af[1][1]=RDA(7,1); \
  STAGE_H(Bsrc, ks2, 1, (CB)*32768 + 24576); \
  asm volatile("s_waitcnt vmcnt(6)" ::: "memory"); \
  PH_MFMA(6, 7) \
}

__device__ __forceinline__ void gemm256_core(
    const __bf16* __restrict__ A, const __bf16* __restrict__ Bm,
    int row0, int col0, __bf16* lds, v4f (&acc)[8][4],
    int wm16, int wn64, int lr, int lg) {
  int t = threadIdx.x;
  int wid = t >> 6;
  int lgc = lg * 16;
  int swl = (lr & 7) << 4;
#pragma unroll
  for (int mm = 0; mm < 8; ++mm)
#pragma unroll
    for (int n = 0; n < 4; ++n) acc[mm][n] = (v4f){0.f, 0.f, 0.f, 0.f};

  // staging addressing: dest linear, source col inverse-swizzled
  int srow = t >> 3;                                     // 0..63
  int scol = (((t & 7) ^ ((t >> 3) & 7)) << 3);          // element col
  const __bf16* Asrc = A  + (size_t)(row0 + srow) * 2048 + scol;
  const __bf16* Bsrc = Bm + (size_t)(col0 + srow) * 2048 + scol;
  int dst0 = wid << 9;                                   // wid*64 chunks * 8 elems

  // prologue: tile0 (4 halves) + Bh0/Ah0/Bh1 of tile1  -> 14 loads
  STAGE_H(Asrc, 0, 0, 0);
  STAGE_H(Asrc, 0, 1, 8192);
  STAGE_H(Bsrc, 0, 0, 16384);
  STAGE_H(Bsrc, 0, 1, 24576);
  STAGE_H(Bsrc, 1, 0, 32768 + 16384);
  STAGE_H(Asrc, 1, 0, 32768);
  STAGE_H(Bsrc, 1, 1, 32768 + 24576);
  asm volatile("s_waitcnt vmcnt(6)" ::: "memory");
  BARR();

  // 32 K-tiles (K=2048), unrolled by 2 for static buffer indices.
  // Tail stages wrap (&31): wrong-but-unread data, keeps vmcnt uniform.
  for (int m = 0; m < 32; m += 2) {
    TILE(0, m + 1, (m + 2) & 31)
    TILE(1, (m + 2) & 31, (m + 3) & 31)
  }
  asm volatile("s_waitcnt vmcnt(0)" ::: "memory");
}

// GEMM1: qkv = x * w_attn^T + b_attn; scatter epilogue -> Q,K (BH,T,D), Vt (BH,D,T)
__global__ __launch_bounds__(512, 2) void gemm_qkv8(
    const __bf16* __restrict__ A, const __bf16* __restrict__ Bm,
    const float* __restrict__ bias,
    __bf16* __restrict__ Qb, __bf16* __restrict__ Kb, __bf16* __restrict__ Vt) {
  extern __shared__ __bf16 lds[];
  int t = threadIdx.x, wid = t >> 6, l = t & 63;
  int lr = l & 15, lg = l >> 4;
  int wm16 = (wid >> 2) * 16, wn64 = (wid & 3) * 64;
  int row0 = blockIdx.x * 256, col0 = blockIdx.y * 256;
  v4f acc[8][4];
  gemm256_core(A, Bm, row0, col0, lds, acc, wm16, wn64, lr, lg);
#pragma unroll
  for (int n = 0; n < 4; ++n) {
    int col = col0 + wn64 + n * 16 + lr;
    int tensor = col >> 11;
    int wc = col & 2047;
    int h = wc >> 7, d = wc & 127;
    float bv = bias[col];
#pragma unroll
    for (int mm = 0; mm < 8; ++mm) {
#pragma unroll
      for (int rr = 0; rr < 4; ++rr) {
        int mg = row0 + wm16 + mm * 32 + lg * 4 + rr;
        int b = mg >> 11, tt = mg & 2047;
        float v = acc[mm][n][rr] + bv;
        size_t bh = (size_t)(b * NHEAD + h);
        if (tensor == 0)      Qb[(bh * T_SEQ + tt) * DHEAD + d] = (__bf16)v;
        else if (tensor == 1) Kb[(bh * T_SEQ + tt) * DHEAD + d] = (__bf16)v;
        else                  Vt[(bh * DHEAD + d) * T_SEQ + tt] = (__bf16)v;
      }
    }
  }
}

// GEMM2: out = Y * w_proj^T + b_proj, fp32 row-major epilogue
__global__ __launch_bounds__(512, 2) void gemm_out8(
    const __bf16* __restrict__ A, const __bf16* __restrict__ Bm,
    const float* __restrict__ bias, float* __restrict__ C) {
  extern __shared__ __bf16 lds[];
  int t = threadIdx.x, wid = t >> 6, l = t & 63;
  int lr = l & 15, lg = l >> 4;
  int wm16 = (wid >> 2) * 16, wn64 = (wid & 3) * 64;
  int row0 = blockIdx.x * 256, col0 = blockIdx.y * 256;
  v4f acc[8][4];
  gemm256_core(A, Bm, row0, col0, lds, acc, wm16, wn64, lr, lg);
#pragma unroll
  for (int n = 0; n < 4; ++n) {
    int col = col0 + wn64 + n * 16 + lr;
    float bv = bias[col];
#pragma unroll
    for (int mm = 0; mm < 8; ++mm) {
#pragma unroll
      for (int rr = 0; rr < 4; ++rr) {
        int mg = row0 + wm16 + mm * 32 + lg * 4 + rr;
        C[(size_t)mg * CDIM + col] = acc[mm][n][rr] + bv;
      }
    }
  }
}

// ---------------- RoPE in-place on Q,K (BH,T,D) ------------------------------
__global__ __launch_bounds__(256) void rope_kernel(__bf16* __restrict__ Qb,
                                                   __bf16* __restrict__ Kb) {
  int idx = blockIdx.x * 256 + threadIdx.x;          // 0 .. 262143
  __bf16* base = (idx & 131072) ? Kb : Qb;
  int r = idx & 131071;                              // row within (BH*T)
  int tt = r & (T_SEQ - 1);
  __bf16* p = base + (size_t)r * DHEAD;
  v8bf xv[16];
#pragma unroll
  for (int j = 0; j < 16; ++j) xv[j] = *(const v8bf*)&p[j * 8];
  v8bf ov[16];
#pragma unroll
  for (int j = 0; j < 64; ++j) {
    float invf = exp2f((float)j * (-13.287712379549449f / 64.f));  // 10000^(-j/64)
    float ang = (float)tt * invf;
    float c = cosf(ang), s = sinf(ang);
    float cps = c + s, cms = c - s;
    float xj   = (float)xv[j >> 3][j & 7];
    float xj64 = (float)xv[(j + 64) >> 3][j & 7];
    float x2j  = (float)xv[(2 * j) >> 3][(2 * j) & 7];
    float x2j1 = (float)xv[(2 * j + 1) >> 3][(2 * j + 1) & 7];
    ov[j >> 3][j & 7]        = (__bf16)(xj * cps - x2j1 * cms);
    ov[(j + 64) >> 3][j & 7] = (__bf16)(xj64 * cps + x2j * cms);
  }
#pragma unroll
  for (int j = 0; j < 16; ++j) *(v8bf*)&p[j * 8] = ov[j];
}

// ---------------- flash attention (LDS-staged K/V, 32 q-rows/wave) ----------
__global__ __launch_bounds__(256) void attn_fwd(
    const __bf16* __restrict__ Qb, const __bf16* __restrict__ Kb,
    const __bf16* __restrict__ Vt, __bf16* __restrict__ Y) {
  __shared__ __bf16 lK[64 * 128];       // 16 KB, [kv][d] swizzled
  __shared__ __bf16 lV[128 * 64];       // 16 KB, [d][kv] swizzled
  __shared__ __bf16 plds[4][32][72];    // 18 KB, per-wave P, padded rows
  int t = threadIdx.x, w = t >> 6, l = t & 63;
  int lr = l & 15, lg = l >> 4;
  int bh = blockIdx.y;
  int b = bh >> 4, h = bh & 15;
  int qb = ((int)gridDim.x - 1 - (int)blockIdx.x) * 128;  // heavy first
  int q0 = qb + w * 32;
  const __bf16* Qh = Qb + (size_t)bh * T_SEQ * DHEAD;
  const __bf16* Kh = Kb + (size_t)bh * T_SEQ * DHEAD;
  const __bf16* Vh = Vt + (size_t)bh * DHEAD * T_SEQ;

  v8bf qf[2][4];
#pragma unroll
  for (int j = 0; j < 2; ++j)
#pragma unroll
    for (int c = 0; c < 4; ++c)
      qf[j][c] = *(const v8bf*)&Qh[(size_t)(q0 + j * 16 + lr) * DHEAD + c * 32 + lg * 8];

  v4f o[2][8];
#pragma unroll
  for (int j = 0; j < 2; ++j)
#pragma unroll
    for (int c = 0; c < 8; ++c) o[j][c] = (v4f){0.f, 0.f, 0.f, 0.f};
  float mrow[2] = {-1e30f, -1e30f}, lrow[2] = {0.f, 0.f};
  const float scale = 0.08838834764831845f;  // 1/sqrt(128)

  int kRow = t >> 4;
  int kSrc = (((t & 15) * 16) ^ ((kRow & 7) << 4)) >> 1;
  int vRow = t >> 3;
  int vSrc = (((t & 7) * 16) ^ ((vRow & 7) << 4)) >> 1;

  int kvEnd = qb + 64;
  for (int kv0 = 0; kv0 <= kvEnd; kv0 += 64) {
    __syncthreads();
#pragma unroll
    for (int i = 0; i < 4; ++i) {
      GLDS16(Kh + (size_t)(kv0 + i * 16 + kRow) * DHEAD + kSrc,
             lK + i * 2048 + w * 512);
      GLDS16(Vh + (size_t)(i * 32 + vRow) * T_SEQ + kv0 + vSrc,
             lV + i * 2048 + w * 512);
    }
    __syncthreads();

    v4f s[2][4];
#pragma unroll
    for (int j = 0; j < 2; ++j)
#pragma unroll
      for (int f = 0; f < 4; ++f) s[j][f] = (v4f){0.f, 0.f, 0.f, 0.f};
#pragma unroll
    for (int f = 0; f < 4; ++f) {
      int row = f * 16 + lr;
      int sw = (row & 7) << 4;
#pragma unroll
      for (int c = 0; c < 4; ++c) {
        v8bf kf = *(const v8bf*)((const char*)lK + row * 256 + ((c * 64 + lg * 16) ^ sw));
        s[0][f] = MFMA16(kf, qf[0][c], s[0][f]);
        s[1][f] = MFMA16(kf, qf[1][c], s[1][f]);
      }
    }

#pragma unroll
    for (int j = 0; j < 2; ++j) {
      int qg = q0 + j * 16 + lr;
      float p[16];
      float mt = -1e30f;
#pragma unroll
      for (int f = 0; f < 4; ++f)
#pragma unroll
        for (int r = 0; r < 4; ++r) {
          float v = s[j][f][r] * scale;
          if (kv0 + f * 16 + lg * 4 + r > qg) v = -1e30f;
          p[f * 4 + r] = v;
          mt = fmaxf(mt, v);
        }
      mt = fmaxf(mt, __shfl_xor(mt, 16));
      mt = fmaxf(mt, __shfl_xor(mt, 32));
      float mnew = fmaxf(mrow[j], mt);
      float corr = __expf(mrow[j] - mnew);
      float psum = 0.f;
#pragma unroll
      for (int r = 0; r < 16; ++r) { p[r] = __expf(p[r] - mnew); psum += p[r]; }
      psum += __shfl_xor(psum, 16);
      psum += __shfl_xor(psum, 32);
      lrow[j] = lrow[j] * corr + psum;
      mrow[j] = mnew;
#pragma unroll
      for (int f = 0; f < 4; ++f) {
        v4bf pv = {(__bf16)p[f * 4], (__bf16)p[f * 4 + 1],
                   (__bf16)p[f * 4 + 2], (__bf16)p[f * 4 + 3]};
        *(v4bf*)&plds[w][j * 16 + lr][f * 16 + lg * 4] = pv;
      }
      float cf[4];
#pragma unroll
      for (int r = 0; r < 4; ++r) cf[r] = __shfl(corr, lg * 4 + r);
#pragma unroll
      for (int c = 0; c < 8; ++c)
#pragma unroll
        for (int r = 0; r < 4; ++r) o[j][c][r] *= cf[r];
    }

    v8bf pa[2][2];
#pragma unroll
    for (int j = 0; j < 2; ++j) {
      pa[j][0] = *(const v8bf*)&plds[w][j * 16 + lr][lg * 8];
      pa[j][1] = *(const v8bf*)&plds[w][j * 16 + lr][32 + lg * 8];
    }
#pragma unroll
    for (int c = 0; c < 8; ++c) {
      int row = c * 16 + lr;
      int sw = (row & 7) << 4;
      v8bf vf0 = *(const v8bf*)((const char*)lV + row * 128 + ((lg * 16) ^ sw));
      v8bf vf1 = *(const v8bf*)((const char*)lV + row * 128 + ((64 + lg * 16) ^ sw));
      o[0][c] = MFMA16(pa[0][0], vf0, o[0][c]);
      o[0][c] = MFMA16(pa[0][1], vf1, o[0][c]);
      o[1][c] = MFMA16(pa[1][0], vf0, o[1][c]);
      o[1][c] = MFMA16(pa[1][1], vf1, o[1][c]);
    }
  }

  size_t ybase = ((size_t)b * T_SEQ) * CDIM + (size_t)h * DHEAD;
#pragma unroll
  for (int j = 0; j < 2; ++j) {
    float lf[4];
#pragma unroll
    for (int r = 0; r < 4; ++r) lf[r] = __shfl(lrow[j], lg * 4 + r);
#pragma unroll
    for (int c = 0; c < 8; ++c) {
#pragma unroll
      for (int r = 0; r < 4; ++r) {
        int qq = q0 + j * 16 + lg * 4 + r;
        Y[ybase + (size_t)qq * CDIM + c * 16 + lr] = (__bf16)(o[j][c][r] / lf[r]);
      }
    }
  }
}

// ---------------- launch -----------------------------------------------------
extern "C" void kernel_launch(void* const* d_in, const int* in_sizes, int n_in,
                              void* d_out, int out_size, void* d_ws, size_t ws_size,
                              hipStream_t stream) {
  const float* x      = (const float*)d_in[0];
  const float* w_attn = (const float*)d_in[1];
  const float* b_attn = (const float*)d_in[2];
  const float* w_proj = (const float*)d_in[3];
  const float* b_proj = (const float*)d_in[4];
  float* out = (float*)d_out;

  char* ws = (char*)d_ws;
  __bf16* xbf  = (__bf16*)(ws);                 // 33,554,432 B; reused as Y
  __bf16* wabf = (__bf16*)(ws + 33554432);      // 25,165,824 B
  __bf16* wpbf = (__bf16*)(ws + 58720256);      //  8,388,608 B
  __bf16* Qb   = (__bf16*)(ws + 67108864);      // 33,554,432 B (BH,T,D)
  __bf16* Kb   = (__bf16*)(ws + 100663296);     // 33,554,432 B (BH,T,D)
  __bf16* Vt   = (__bf16*)(ws + 134217728);     // 33,554,432 B (BH,D,T)
  __bf16* Y    = xbf;

  // allow 128 KiB dynamic LDS (no-op if not required on this ROCm)
  (void)hipFuncSetAttribute((const void*)gemm_qkv8,
                            hipFuncAttributeMaxDynamicSharedMemorySize, 131072);
  (void)hipFuncSetAttribute((const void*)gemm_out8,
                            hipFuncAttributeMaxDynamicSharedMemorySize, 131072);

  cvt_f32_bf16<<<1024, 256, 0, stream>>>(x, xbf, 16777216);
  cvt_f32_bf16<<<1024, 256, 0, stream>>>(w_attn, wabf, 12582912);
  cvt_f32_bf16<<<512, 256, 0, stream>>>(w_proj, wpbf, 4194304);

  gemm_qkv8<<<dim3(32, 24), 512, 131072, stream>>>(xbf, wabf, b_attn, Qb, Kb, Vt);

  rope_kernel<<<1024, 256, 0, stream>>>(Qb, Kb);

  attn_fwd<<<dim3(16, 64), 256, 0, stream>>>(Qb, Kb, Vt, Y);

  gemm_out8<<<dim3(32, 8), 512, 131072, stream>>>(Y, wpbf, b_proj, out);
}